// Round 1
// baseline (1127.250 us; speedup 1.0000x reference)
//
#include <hip/hip_runtime.h>
#include <hip/hip_bf16.h>
#include <math.h>

// Problem constants
#define S_   64
#define BS_  8
#define NN_  32
#define R_   8
#define H_   512
#define EMB_ 256
// scale = 1/sqrt(8)
#define SCALE_ 0.35355339059327373f

__device__ __forceinline__ float gelu_exact(float x) {
    return 0.5f * x * (1.0f + erff(x * 0.70710678118654752440f));
}

// ---------------------------------------------------------------------------
// pe[p][2j] = sin(p*div_j), pe[p][2j+1] = cos(p*div_j), div_j = 10000^(2j/512)
// Replicate f32 pipeline: div rounded to f32, ang = p*div in f32, then exact trig.
__global__ void pe_kernel(float* __restrict__ pe) {
    int p = blockIdx.x;      // 0..64
    int j = threadIdx.x;     // 0..255
    double ex = (double)(2 * j) / 512.0;
    float divf = (float)exp(ex * 9.210340371976184);  // ln(10000)
    float ang = (float)p * divf;                       // f32 rounding matters
    double a = (double)ang;
    pe[p * H_ + 2 * j]     = (float)sin(a);
    pe[p * H_ + 2 * j + 1] = (float)cos(a);
}

// ---------------------------------------------------------------------------
// e0[b,h] = gelu(gelu(node_bias[src0]) + pe[0]);  src0 = nid[b,0,0,0]
__global__ void e0_kernel(const int* __restrict__ nid,
                          const float* __restrict__ node_bias,
                          const float* __restrict__ pe,
                          float* __restrict__ e_all) {
    int b = blockIdx.x;
    int t = threadIdx.x;
    int src0 = nid[((b * S_ + 0) * NN_ + 0) * 2 + 0];
    for (int h = t; h < H_; h += 256) {
        float g = gelu_exact(node_bias[src0 * H_ + h]);
        e_all[b * H_ + h] = gelu_exact(g + pe[h]);  // e_all[(i=0)*8+b]
    }
}

// ---------------------------------------------------------------------------
// U0[i,b,r,h] = Wl @ emb[src(i,b,0)] + wl_b ; V0 likewise with tgt / Wr.
// grid (32 pair-tiles, 16 row-tiles, 2 uv), block 256.
__global__ void uv0_kernel(const int* __restrict__ nid,
                           const float* __restrict__ node_emb,
                           const float* __restrict__ wl_w, const float* __restrict__ wl_b,
                           const float* __restrict__ wr_w, const float* __restrict__ wr_b,
                           float* __restrict__ U0, float* __restrict__ V0) {
    __shared__ float emb_s[16][EMB_];
    int pt = blockIdx.x, rt = blockIdx.y, uv = blockIdx.z;
    int t = threadIdx.x;
    for (int k = 0; k < 16; ++k) {
        int pair = pt * 16 + k;
        int i = pair >> 3, b = pair & 7;
        int id = nid[((b * S_ + i) * NN_ + 0) * 2 + uv];
        emb_s[k][t] = node_emb[id * EMB_ + t];
    }
    __syncthreads();
    int row = rt * 256 + t;  // 0..4095 = r*512+h
    const float* W  = uv ? wr_w : wl_w;
    const float* Bb = uv ? wr_b : wl_b;
    const float4* w4 = (const float4*)(W + row * EMB_);
    float acc[16];
#pragma unroll
    for (int m = 0; m < 16; ++m) acc[m] = 0.f;
    for (int c4 = 0; c4 < 64; ++c4) {
        float4 w = w4[c4];
#pragma unroll
        for (int m = 0; m < 16; ++m) {
            float4 em = ((const float4*)emb_s[m])[c4];
            acc[m] = fmaf(w.x, em.x, fmaf(w.y, em.y, fmaf(w.z, em.z, fmaf(w.w, em.w, acc[m]))));
        }
    }
    float bb = Bb[row];
    float* OUT = uv ? V0 : U0;
#pragma unroll
    for (int m = 0; m < 16; ++m) {
        int pair = pt * 16 + m;
        OUT[pair * (R_ * H_) + row] = acc[m] + bb;
    }
}

// ---------------------------------------------------------------------------
// Sequential chain, one block per batch b (independent!). 512 threads.
// Per step: e_i -> proj(n=0) via U0 -> out(n=0) via V0 -> running softmax-mean.
__global__ void seq_kernel(const int* __restrict__ nid,
                           const float* __restrict__ positions,
                           const float* __restrict__ U0, const float* __restrict__ V0,
                           const float* __restrict__ bias_base,
                           const float* __restrict__ node_bias,
                           const float* __restrict__ pe,
                           float* __restrict__ e_all) {
    __shared__ float e_s[H_];
    __shared__ float proj_s[R_];
    int b = blockIdx.x;
    int t = threadIdx.x;        // = h
    int w = t >> 6, l = t & 63;
    float run = 0.f, denom = 0.f;
    for (int i = 0; i < S_; ++i) {
        float ereg = (i == 0) ? e_all[b * H_ + t] : (run / denom);
        e_s[t] = ereg;
        e_all[(i * BS_ + b) * H_ + t] = ereg;
        __syncthreads();
        // proj[r=w] = sum_h e[h] * U0[i,b,w,h]  (wave w owns r=w)
        const float* Ur = U0 + ((i * BS_ + b) * R_ + w) * H_;
        float p = 0.f;
#pragma unroll
        for (int k = 0; k < 8; ++k) {
            int h = l + 64 * k;
            p = fmaf(e_s[h], Ur[h], p);
        }
#pragma unroll
        for (int off = 32; off; off >>= 1) p += __shfl_down(p, off, 64);
        if (l == 0) proj_s[w] = p;
        __syncthreads();
        // out(n=0)[h=t]
        int tgt0 = nid[((b * S_ + i) * NN_ + 0) * 2 + 1];
        const float* Vb = V0 + (i * BS_ + b) * (R_ * H_);
        float v = 0.f;
#pragma unroll
        for (int r = 0; r < R_; ++r) v = fmaf(proj_s[r], Vb[r * H_ + t], v);
        float val = fmaf(v, SCALE_, bias_base[t] + node_bias[tgt0 * H_ + t] + pe[(i + 1) * H_ + t]);
        float o = gelu_exact(val);
        float ep = expf(positions[i]);
        run = fmaf(ep, o, run);
        denom += ep;
        __syncthreads();
    }
}

// ---------------------------------------------------------------------------
// A[i,b,r,c] = sum_h e_all[i,b,h] * wl_w[r*512+h, c].  grid (32,8), block 256 (t=c).
__global__ void a_kernel(const float* __restrict__ e_all,
                         const float* __restrict__ wl_w,
                         float* __restrict__ A) {
    __shared__ float e_s[16][H_];  // 32 kB
    int pt = blockIdx.x, r = blockIdx.y, c = threadIdx.x;
    for (int k = 0; k < 32; ++k) {
        int idx = k * 256 + c;
        int mm = idx >> 9, h = idx & 511;
        e_s[mm][h] = e_all[(pt * 16 + mm) * H_ + h];
    }
    __syncthreads();
    float acc[16];
#pragma unroll
    for (int m = 0; m < 16; ++m) acc[m] = 0.f;
    const float* W = wl_w + r * H_ * EMB_ + c;
    for (int h4 = 0; h4 < 128; ++h4) {
        float w0 = W[(4 * h4 + 0) * EMB_];
        float w1 = W[(4 * h4 + 1) * EMB_];
        float w2 = W[(4 * h4 + 2) * EMB_];
        float w3 = W[(4 * h4 + 3) * EMB_];
#pragma unroll
        for (int m = 0; m < 16; ++m) {
            float4 e4 = ((const float4*)e_s[m])[h4];
            acc[m] = fmaf(w0, e4.x, fmaf(w1, e4.y, fmaf(w2, e4.z, fmaf(w3, e4.w, acc[m]))));
        }
    }
#pragma unroll
    for (int m = 0; m < 16; ++m)
        A[((pt * 16 + m) * R_ + r) * EMB_ + c] = acc[m];
}

// cb[pair,r] = sum_h e_all[pair,h] * wl_b[r*512+h]   (wl_b==0 in given inputs)
__global__ void cb_kernel(const float* __restrict__ e_all,
                          const float* __restrict__ wl_b,
                          float* __restrict__ cb) {
    int pair = blockIdx.x;
    int l = threadIdx.x;  // 64
    for (int r = 0; r < R_; ++r) {
        float p = 0.f;
#pragma unroll
        for (int k = 0; k < 8; ++k) {
            int h = l + 64 * k;
            p = fmaf(e_all[pair * H_ + h], wl_b[r * H_ + h], p);
        }
#pragma unroll
        for (int off = 32; off; off >>= 1) p += __shfl_down(p, off, 64);
        if (l == 0) cb[pair * R_ + r] = p;
    }
}

// ---------------------------------------------------------------------------
// proj[i,b,n,r] = A[i,b,r,:]·emb[src(i,b,n)] + cb[i,b,r].  grid 512 (pair), block 256.
__global__ void proj_kernel(const int* __restrict__ nid,
                            const float* __restrict__ node_emb,
                            const float* __restrict__ A,
                            const float* __restrict__ cb,
                            float* __restrict__ proj) {
    __shared__ float A_s[R_][EMB_];
    __shared__ float cb_s[R_];
    int pair = blockIdx.x;
    int t = threadIdx.x;
    int w = t >> 6, l = t & 63;
    int i = pair >> 3, b = pair & 7;
    for (int k = 0; k < 8; ++k) A_s[k][t] = A[pair * (R_ * EMB_) + k * 256 + t];
    if (t < 8) cb_s[t] = cb[pair * R_ + t];
    __syncthreads();
    float4 a4 = ((const float4*)A_s[w])[l];
    for (int n = 0; n < NN_; ++n) {
        int id = nid[((b * S_ + i) * NN_ + n) * 2 + 0];
        float4 em = ((const float4*)(node_emb + id * EMB_))[l];
        float p = a4.x * em.x + a4.y * em.y + a4.z * em.z + a4.w * em.w;
#pragma unroll
        for (int off = 32; off; off >>= 1) p += __shfl_down(p, off, 64);
        if (l == 0) proj[(pair * NN_ + n) * R_ + w] = p + cb_s[w];
    }
}

// ---------------------------------------------------------------------------
// The heavy fused kernel: for each (i,b,n):
//   nxt[h] = SCALE * sum_r proj[r]*(wr_w[r*512+h,:]·emb_tgt + wr_b[r*512+h])
//            + bias_base[h] + node_bias[tgt,h] + pe[i+1,h]
//   energy = || gelu(nxt) ||
// grid (512 pairs, 2 n-halves), block 256; each thread owns h and h+256, 16 n's.
__global__ __launch_bounds__(256) void big_kernel(
        const int* __restrict__ nid, const float* __restrict__ node_emb,
        const float* __restrict__ wr_w, const float* __restrict__ wr_b,
        const float* __restrict__ bias_base, const float* __restrict__ node_bias,
        const float* __restrict__ pe, const float* __restrict__ proj,
        float* __restrict__ energy) {
    __shared__ float emb_s[16][EMB_];   // 16 kB
    __shared__ float proj_s[16][R_];
    __shared__ int   tgt_s[16];
    __shared__ float red_s[16][4];
    int pair = blockIdx.x, half = blockIdx.y;
    int i = pair >> 3, b = pair & 7;
    int t = threadIdx.x;
    int n0 = half * 16;
    for (int k = 0; k < 16; ++k) {
        int id = nid[((b * S_ + i) * NN_ + (n0 + k)) * 2 + 1];
        emb_s[k][t] = node_emb[id * EMB_ + t];
        if (t == 0) tgt_s[k] = id;
    }
    if (t < 128) {
        int nn = t >> 3, r = t & 7;
        proj_s[nn][r] = proj[(pair * NN_ + n0 + nn) * R_ + r];
    }
    __syncthreads();
    int h0 = t, h1 = t + 256;
    float nxt0[16], nxt1[16];
#pragma unroll
    for (int n = 0; n < 16; ++n) { nxt0[n] = 0.f; nxt1[n] = 0.f; }
    for (int r = 0; r < R_; ++r) {
        const float4* w04 = (const float4*)(wr_w + (r * H_ + h0) * EMB_);
        const float4* w14 = (const float4*)(wr_w + (r * H_ + h1) * EMB_);
        float v0[16], v1[16];
#pragma unroll
        for (int n = 0; n < 16; ++n) { v0[n] = 0.f; v1[n] = 0.f; }
        for (int c4 = 0; c4 < 64; ++c4) {
            float4 a  = w04[c4];
            float4 bw = w14[c4];
#pragma unroll
            for (int n = 0; n < 16; ++n) {
                float4 em = ((const float4*)emb_s[n])[c4];
                v0[n] = fmaf(a.x,  em.x, fmaf(a.y,  em.y, fmaf(a.z,  em.z, fmaf(a.w,  em.w, v0[n]))));
                v1[n] = fmaf(bw.x, em.x, fmaf(bw.y, em.y, fmaf(bw.z, em.z, fmaf(bw.w, em.w, v1[n]))));
            }
        }
        float wb0 = wr_b[r * H_ + h0];
        float wb1 = wr_b[r * H_ + h1];
#pragma unroll
        for (int n = 0; n < 16; ++n) {
            float pj = proj_s[n][r];
            nxt0[n] = fmaf(pj, v0[n] + wb0, nxt0[n]);
            nxt1[n] = fmaf(pj, v1[n] + wb1, nxt1[n]);
        }
    }
    float base0 = bias_base[h0] + pe[(i + 1) * H_ + h0];
    float base1 = bias_base[h1] + pe[(i + 1) * H_ + h1];
    int w = t >> 6, l = t & 63;
#pragma unroll
    for (int n = 0; n < 16; ++n) {
        int tgt = tgt_s[n];
        float o0 = gelu_exact(fmaf(nxt0[n], SCALE_, base0 + node_bias[tgt * H_ + h0]));
        float o1 = gelu_exact(fmaf(nxt1[n], SCALE_, base1 + node_bias[tgt * H_ + h1]));
        float sq = fmaf(o0, o0, o1 * o1);
#pragma unroll
        for (int off = 32; off; off >>= 1) sq += __shfl_down(sq, off, 64);
        if (l == 0) red_s[n][w] = sq;
    }
    __syncthreads();
    if (t < 16) {
        float ssum = red_s[t][0] + red_s[t][1] + red_s[t][2] + red_s[t][3];
        energy[pair * NN_ + n0 + t] = sqrtf(ssum);
    }
}

// ---------------------------------------------------------------------------
// loss = (1/512) * sum_{i,b} [ logsumexp_n(energy) - energy[n=0] ]
__global__ void loss_kernel(const float* __restrict__ energy, float* __restrict__ out) {
    __shared__ float red[8];
    int t = threadIdx.x;  // 512 = pairs
    float en[NN_];
    float mx = -1e30f;
#pragma unroll
    for (int n = 0; n < NN_; ++n) {
        en[n] = energy[t * NN_ + n];
        mx = fmaxf(mx, en[n]);
    }
    float s = 0.f;
#pragma unroll
    for (int n = 0; n < NN_; ++n) s += expf(en[n] - mx);
    float li = logf(s) + mx - en[0];
#pragma unroll
    for (int off = 32; off; off >>= 1) li += __shfl_down(li, off, 64);
    if ((t & 63) == 0) red[t >> 6] = li;
    __syncthreads();
    if (t == 0) {
        float tot = 0.f;
#pragma unroll
        for (int w = 0; w < 8; ++w) tot += red[w];
        out[0] = tot / 512.0f;
    }
}

// ---------------------------------------------------------------------------
extern "C" void kernel_launch(void* const* d_in, const int* in_sizes, int n_in,
                              void* d_out, int out_size, void* d_ws, size_t ws_size,
                              hipStream_t stream) {
    const int*   nid       = (const int*)d_in[0];
    const float* node_emb  = (const float*)d_in[1];
    const float* wl_w      = (const float*)d_in[2];
    const float* wl_b      = (const float*)d_in[3];
    const float* wr_w      = (const float*)d_in[4];
    const float* wr_b      = (const float*)d_in[5];
    const float* bias_base = (const float*)d_in[6];
    const float* node_bias = (const float*)d_in[7];
    const float* positions = (const float*)d_in[8];
    float* out = (float*)d_out;

    float* ws     = (float*)d_ws;
    float* pe     = ws;                 // 65*512          = 33280
    float* e_all  = pe + 65 * H_;       // 64*8*512        = 262144
    float* U0     = e_all + S_ * BS_ * H_;          // 64*8*8*512 = 2097152
    float* V0     = U0 + S_ * BS_ * R_ * H_;        // 2097152
    float* A      = V0 + S_ * BS_ * R_ * H_;        // 64*8*8*256 = 1048576
    float* cb     = A + S_ * BS_ * R_ * EMB_;       // 4096
    float* proj   = cb + S_ * BS_ * R_;             // 64*8*32*8  = 131072
    float* energy = proj + S_ * BS_ * NN_ * R_;     // 16384
    // total ~5.6M floats = 22.5 MB of d_ws

    pe_kernel<<<65, 256, 0, stream>>>(pe);
    e0_kernel<<<8, 256, 0, stream>>>(nid, node_bias, pe, e_all);
    uv0_kernel<<<dim3(32, 16, 2), 256, 0, stream>>>(nid, node_emb, wl_w, wl_b, wr_w, wr_b, U0, V0);
    seq_kernel<<<8, 512, 0, stream>>>(nid, positions, U0, V0, bias_base, node_bias, pe, e_all);
    a_kernel<<<dim3(32, 8), 256, 0, stream>>>(e_all, wl_w, A);
    cb_kernel<<<512, 64, 0, stream>>>(e_all, wl_b, cb);
    proj_kernel<<<512, 256, 0, stream>>>(nid, node_emb, A, cb, proj);
    big_kernel<<<dim3(512, 2), 256, 0, stream>>>(nid, node_emb, wr_w, wr_b, bias_base, node_bias, pe, proj, energy);
    loss_kernel<<<1, 512, 0, stream>>>(energy, out);
}

// Round 2
// 364.493 us; speedup vs baseline: 3.0927x; 3.0927x over previous
//
#include <hip/hip_runtime.h>
#include <hip/hip_bf16.h>
#include <math.h>

// Problem constants
#define S_   64
#define BS_  8
#define NN_  32
#define R_   8
#define H_   512
#define EMB_ 256
#define NT_  16384   // triples = S_*BS_*NN_
#define SCALE_ 0.35355339059327373f

typedef __attribute__((ext_vector_type(8))) short bf16x8;
typedef __attribute__((ext_vector_type(4))) float f32x4;
typedef __attribute__((ext_vector_type(4))) int i32x4;

__device__ __forceinline__ float gelu_exact(float x) {
    return 0.5f * x * (1.0f + erff(x * 0.70710678118654752440f));
}

__device__ __forceinline__ unsigned short f2bf(float v) {
    union { float f; unsigned int u; } c; c.f = v;
    unsigned int lsb = (c.u >> 16) & 1;
    c.u += 0x7fff + lsb;   // round-to-nearest-even
    return (unsigned short)(c.u >> 16);
}

// ---------------------------------------------------------------------------
__global__ void pe_kernel(float* __restrict__ pe) {
    int p = blockIdx.x;      // 0..64
    int j = threadIdx.x;     // 0..255
    double ex = (double)(2 * j) / 512.0;
    float divf = (float)exp(ex * 9.210340371976184);  // ln(10000)
    float ang = (float)p * divf;                       // f32 rounding matters
    double a = (double)ang;
    pe[p * H_ + 2 * j]     = (float)sin(a);
    pe[p * H_ + 2 * j + 1] = (float)cos(a);
}

// ---------------------------------------------------------------------------
__global__ void e0_kernel(const int* __restrict__ nid,
                          const float* __restrict__ node_bias,
                          const float* __restrict__ pe,
                          float* __restrict__ e_all) {
    int b = blockIdx.x;
    int t = threadIdx.x;
    int src0 = nid[((b * S_ + 0) * NN_ + 0) * 2 + 0];
    for (int h = t; h < H_; h += 256) {
        float g = gelu_exact(node_bias[src0 * H_ + h]);
        e_all[b * H_ + h] = gelu_exact(g + pe[h]);
    }
}

// ---------------------------------------------------------------------------
// U0/V0 for the n=0 neighbors (needed by the sequential chain).
__global__ void uv0_kernel(const int* __restrict__ nid,
                           const float* __restrict__ node_emb,
                           const float* __restrict__ wl_w, const float* __restrict__ wl_b,
                           const float* __restrict__ wr_w, const float* __restrict__ wr_b,
                           float* __restrict__ U0, float* __restrict__ V0) {
    __shared__ float emb_s[16][EMB_];
    int pt = blockIdx.x, rt = blockIdx.y, uv = blockIdx.z;
    int t = threadIdx.x;
    for (int k = 0; k < 16; ++k) {
        int pair = pt * 16 + k;
        int i = pair >> 3, b = pair & 7;
        int id = nid[((b * S_ + i) * NN_ + 0) * 2 + uv];
        emb_s[k][t] = node_emb[id * EMB_ + t];
    }
    __syncthreads();
    int row = rt * 256 + t;
    const float* W  = uv ? wr_w : wl_w;
    const float* Bb = uv ? wr_b : wl_b;
    const float4* w4 = (const float4*)(W + row * EMB_);
    float acc[16];
#pragma unroll
    for (int m = 0; m < 16; ++m) acc[m] = 0.f;
    for (int c4 = 0; c4 < 64; ++c4) {
        float4 w = w4[c4];
#pragma unroll
        for (int m = 0; m < 16; ++m) {
            float4 em = ((const float4*)emb_s[m])[c4];
            acc[m] = fmaf(w.x, em.x, fmaf(w.y, em.y, fmaf(w.z, em.z, fmaf(w.w, em.w, acc[m]))));
        }
    }
    float bb = Bb[row];
    float* OUT = uv ? V0 : U0;
#pragma unroll
    for (int m = 0; m < 16; ++m) {
        int pair = pt * 16 + m;
        OUT[pair * (R_ * H_) + row] = acc[m] + bb;
    }
}

// ---------------------------------------------------------------------------
__global__ void seq_kernel(const int* __restrict__ nid,
                           const float* __restrict__ positions,
                           const float* __restrict__ U0, const float* __restrict__ V0,
                           const float* __restrict__ bias_base,
                           const float* __restrict__ node_bias,
                           const float* __restrict__ pe,
                           float* __restrict__ e_all) {
    __shared__ float e_s[H_];
    __shared__ float proj_s[R_];
    int b = blockIdx.x;
    int t = threadIdx.x;
    int w = t >> 6, l = t & 63;
    float run = 0.f, denom = 0.f;
    for (int i = 0; i < S_; ++i) {
        float ereg = (i == 0) ? e_all[b * H_ + t] : (run / denom);
        e_s[t] = ereg;
        e_all[(i * BS_ + b) * H_ + t] = ereg;
        __syncthreads();
        const float* Ur = U0 + ((i * BS_ + b) * R_ + w) * H_;
        float p = 0.f;
#pragma unroll
        for (int k = 0; k < 8; ++k) {
            int h = l + 64 * k;
            p = fmaf(e_s[h], Ur[h], p);
        }
#pragma unroll
        for (int off = 32; off; off >>= 1) p += __shfl_down(p, off, 64);
        if (l == 0) proj_s[w] = p;
        __syncthreads();
        int tgt0 = nid[((b * S_ + i) * NN_ + 0) * 2 + 1];
        const float* Vb = V0 + (i * BS_ + b) * (R_ * H_);
        float v = 0.f;
#pragma unroll
        for (int r = 0; r < R_; ++r) v = fmaf(proj_s[r], Vb[r * H_ + t], v);
        float val = fmaf(v, SCALE_, bias_base[t] + node_bias[tgt0 * H_ + t] + pe[(i + 1) * H_ + t]);
        float o = gelu_exact(val);
        float ep = expf(positions[i]);
        run = fmaf(ep, o, run);
        denom += ep;
        __syncthreads();
    }
}

// ---------------------------------------------------------------------------
// A[i,b,r,c] = sum_h e_all[i,b,h] * wl_w[r*512+h, c]
__global__ void a_kernel(const float* __restrict__ e_all,
                         const float* __restrict__ wl_w,
                         float* __restrict__ A) {
    __shared__ float e_s[16][H_];
    int pt = blockIdx.x, r = blockIdx.y, c = threadIdx.x;
    for (int k = 0; k < 32; ++k) {
        int idx = k * 256 + c;
        int mm = idx >> 9, h = idx & 511;
        e_s[mm][h] = e_all[(pt * 16 + mm) * H_ + h];
    }
    __syncthreads();
    float acc[16];
#pragma unroll
    for (int m = 0; m < 16; ++m) acc[m] = 0.f;
    const float* W = wl_w + r * H_ * EMB_ + c;
    for (int h4 = 0; h4 < 128; ++h4) {
        float w0 = W[(4 * h4 + 0) * EMB_];
        float w1 = W[(4 * h4 + 1) * EMB_];
        float w2 = W[(4 * h4 + 2) * EMB_];
        float w3 = W[(4 * h4 + 3) * EMB_];
#pragma unroll
        for (int m = 0; m < 16; ++m) {
            float4 e4 = ((const float4*)e_s[m])[h4];
            acc[m] = fmaf(w0, e4.x, fmaf(w1, e4.y, fmaf(w2, e4.z, fmaf(w3, e4.w, acc[m]))));
        }
    }
#pragma unroll
    for (int m = 0; m < 16; ++m)
        A[((pt * 16 + m) * R_ + r) * EMB_ + c] = acc[m];
}

__global__ void cb_kernel(const float* __restrict__ e_all,
                          const float* __restrict__ wl_b,
                          float* __restrict__ cb) {
    int pair = blockIdx.x;
    int l = threadIdx.x;
    for (int r = 0; r < R_; ++r) {
        float p = 0.f;
#pragma unroll
        for (int k = 0; k < 8; ++k) {
            int h = l + 64 * k;
            p = fmaf(e_all[pair * H_ + h], wl_b[r * H_ + h], p);
        }
#pragma unroll
        for (int off = 32; off; off >>= 1) p += __shfl_down(p, off, 64);
        if (l == 0) cb[pair * R_ + r] = p;
    }
}

// ---------------------------------------------------------------------------
__global__ void proj_kernel(const int* __restrict__ nid,
                            const float* __restrict__ node_emb,
                            const float* __restrict__ A,
                            const float* __restrict__ cb,
                            float* __restrict__ proj) {
    __shared__ float A_s[R_][EMB_];
    __shared__ float cb_s[R_];
    int pair = blockIdx.x;
    int t = threadIdx.x;
    int w = t >> 6, l = t & 63;
    int i = pair >> 3, b = pair & 7;
    for (int k = 0; k < 8; ++k) A_s[k][t] = A[pair * (R_ * EMB_) + k * 256 + t];
    if (t < 8) cb_s[t] = cb[pair * R_ + t];
    __syncthreads();
    float4 a4 = ((const float4*)A_s[w])[l];
    for (int n = 0; n < NN_; ++n) {
        int id = nid[((b * S_ + i) * NN_ + n) * 2 + 0];
        float4 em = ((const float4*)(node_emb + id * EMB_))[l];
        float p = a4.x * em.x + a4.y * em.y + a4.z * em.z + a4.w * em.w;
#pragma unroll
        for (int off = 32; off; off >>= 1) p += __shfl_down(p, off, 64);
        if (l == 0) proj[(pair * NN_ + n) * R_ + w] = p + cb_s[w];
    }
}

// ---------------------------------------------------------------------------
// W2[nIdx][c] (bf16), nIdx = hb*128 + r*16 + hl  <-  wr_w[r*512 + hb*16+hl][c]
__global__ void prep_w2(const float* __restrict__ wr_w, const float* __restrict__ wr_b,
                        unsigned short* __restrict__ W2, float* __restrict__ wrb2) {
    int nIdx = blockIdx.x;  // 4096
    int t = threadIdx.x;    // 256
    int hb = nIdx >> 7, r = (nIdx >> 4) & 7, hl = nIdx & 15;
    int src = r * H_ + hb * 16 + hl;
    W2[nIdx * EMB_ + t] = f2bf(wr_w[src * EMB_ + t]);
    if (t == 0) wrb2[nIdx] = wr_b[src];
}

// ---------------------------------------------------------------------------
// Etgt[trip][c] (bf16) = node_emb[tgt(trip)][c];  tgt_ids[trip] = tgt
__global__ void gather_tgt(const int* __restrict__ nid, const float* __restrict__ node_emb,
                           unsigned short* __restrict__ Etgt, int* __restrict__ tgt_ids) {
    int trip = blockIdx.x;   // 16384 ; trip = (i*8+b)*32 + n
    int t = threadIdx.x;     // 256
    int i = trip >> 8, b = (trip >> 5) & 7, n = trip & 31;
    int id = nid[((b * S_ + i) * NN_ + n) * 2 + 1];
    if (t == 0) tgt_ids[trip] = id;
    Etgt[trip * EMB_ + t] = f2bf(node_emb[id * EMB_ + t]);
}

// ---------------------------------------------------------------------------
// MFMA GEMM + fused epilogue.
// grid (128 M-tiles, 32 hb), block 256 = 4 waves; wave tile 32x128; BK=64.
// Output: energy_part[trip][hb] = sum over the 16 h's of gelu(nxt)^2
__global__ __launch_bounds__(256) void gemm_big(
        const unsigned short* __restrict__ W2, const float* __restrict__ wrb2,
        const unsigned short* __restrict__ Etgt, const int* __restrict__ tgt_ids,
        const float* __restrict__ proj, const float* __restrict__ bias_base,
        const float* __restrict__ node_bias, const float* __restrict__ pe,
        float* __restrict__ energy_part) {
    __shared__ unsigned short Als[128 * 64];   // 16 KB, XOR-swizzled rows
    __shared__ unsigned short Bls[128 * 64];   // 16 KB
    __shared__ float proj_s[128 * R_];         // 4 KB
    __shared__ float wrb_s[128];
    int blkM = blockIdx.x;   // 0..127 (triple tiles)
    int hb   = blockIdx.y;   // 0..31  (h tiles of 16)
    int t = threadIdx.x;
    int w = t >> 6, l = t & 63;

    // stage proj for this block's 128 triples + wrb for these 128 cols
    ((float4*)proj_s)[t] = ((const float4*)(proj + blkM * 128 * R_))[t];
    if (t < 128) wrb_s[t] = wrb2[hb * 128 + t];

    const unsigned short* Ag = Etgt + (size_t)blkM * 128 * EMB_;
    const unsigned short* Bg = W2 + (size_t)hb * 128 * EMB_;

    int srow = t >> 1, shalf = t & 1;          // staging: row, 64B-half
    const int sgoff = srow * EMB_ + shalf * 32;  // ushort offset into 256-K row

    f32x4 acc[2][8];
#pragma unroll
    for (int m = 0; m < 2; ++m)
#pragma unroll
        for (int r = 0; r < 8; ++r) acc[m][r] = (f32x4)0.f;

    i32x4 ar[4], br[4];
    // prologue: load k-step 0
    {
        const i32x4* ap = (const i32x4*)(Ag + sgoff);
        const i32x4* bp = (const i32x4*)(Bg + sgoff);
#pragma unroll
        for (int q = 0; q < 4; ++q) { ar[q] = ap[q]; br[q] = bp[q]; }
    }
    const int swz = (srow & 7) << 4;
    const int wbase = srow * 128;

    for (int ks = 0; ks < 4; ++ks) {
        __syncthreads();   // previous compute done reading LDS
#pragma unroll
        for (int q = 0; q < 4; ++q) {
            int ba = wbase + ((shalf * 64 + q * 16) ^ swz);
            *(i32x4*)((char*)Als + ba) = ar[q];
            *(i32x4*)((char*)Bls + ba) = br[q];
        }
        __syncthreads();
        if (ks < 3) {
            const i32x4* ap = (const i32x4*)(Ag + sgoff + (ks + 1) * 64);
            const i32x4* bp = (const i32x4*)(Bg + sgoff + (ks + 1) * 64);
#pragma unroll
            for (int q = 0; q < 4; ++q) { ar[q] = ap[q]; br[q] = bp[q]; }
        }
#pragma unroll
        for (int kk2 = 0; kk2 < 2; ++kk2) {
            bf16x8 af[2], bf[8];
#pragma unroll
            for (int mf = 0; mf < 2; ++mf) {
                int row = w * 32 + mf * 16 + (l & 15);
                int ba = row * 128 + (((kk2 * 64) + ((l >> 4) * 16)) ^ ((row & 7) << 4));
                af[mf] = *(const bf16x8*)((const char*)Als + ba);
            }
#pragma unroll
            for (int r = 0; r < 8; ++r) {
                int row = r * 16 + (l & 15);
                int ba = row * 128 + (((kk2 * 64) + ((l >> 4) * 16)) ^ ((row & 7) << 4));
                bf[r] = *(const bf16x8*)((const char*)Bls + ba);
            }
#pragma unroll
            for (int mf = 0; mf < 2; ++mf)
#pragma unroll
                for (int r = 0; r < 8; ++r)
                    acc[mf][r] = __builtin_amdgcn_mfma_f32_16x16x32_bf16(
                        af[mf], bf[r], acc[mf][r], 0, 0, 0);
        }
    }

    // epilogue: contract r with proj, add biases, gelu, square, reduce 16 h
    int hl = l & 15;
    int h = hb * 16 + hl;
    float bb_pe_base = bias_base[h];
    float wrb_l[8];
#pragma unroll
    for (int r = 0; r < 8; ++r) wrb_l[r] = wrb_s[r * 16 + hl];
#pragma unroll
    for (int mf = 0; mf < 2; ++mf) {
#pragma unroll
        for (int reg = 0; reg < 4; ++reg) {
            int tl = w * 32 + mf * 16 + (l >> 4) * 4 + reg;
            int trip = blkM * 128 + tl;
            int i = trip >> 8;
            int tgt = tgt_ids[trip];
            float nxt = 0.f;
#pragma unroll
            for (int r = 0; r < 8; ++r)
                nxt = fmaf(proj_s[tl * R_ + r], acc[mf][r][reg] + wrb_l[r], nxt);
            float val = fmaf(nxt, SCALE_,
                             bb_pe_base + node_bias[(size_t)tgt * H_ + h] + pe[(i + 1) * H_ + h]);
            float o = gelu_exact(val);
            float sq = o * o;
#pragma unroll
            for (int mask = 1; mask < 16; mask <<= 1) sq += __shfl_xor(sq, mask, 64);
            if (hl == 0) energy_part[(size_t)trip * 32 + hb] = sq;
        }
    }
}

// ---------------------------------------------------------------------------
__global__ void energy_reduce(const float* __restrict__ part, float* __restrict__ energy) {
    int idx = blockIdx.x * 256 + threadIdx.x;  // 16384
    const float4* p = (const float4*)(part + (size_t)idx * 32);
    float s = 0.f;
#pragma unroll
    for (int q = 0; q < 8; ++q) {
        float4 v = p[q];
        s += v.x + v.y + v.z + v.w;
    }
    energy[idx] = sqrtf(s);
}

// ---------------------------------------------------------------------------
__global__ void loss_kernel(const float* __restrict__ energy, float* __restrict__ out) {
    __shared__ float red[8];
    int t = threadIdx.x;  // 512 = pairs
    float en[NN_];
    float mx = -1e30f;
#pragma unroll
    for (int n = 0; n < NN_; ++n) {
        en[n] = energy[t * NN_ + n];
        mx = fmaxf(mx, en[n]);
    }
    float s = 0.f;
#pragma unroll
    for (int n = 0; n < NN_; ++n) s += expf(en[n] - mx);
    float li = logf(s) + mx - en[0];
#pragma unroll
    for (int off = 32; off; off >>= 1) li += __shfl_down(li, off, 64);
    if ((t & 63) == 0) red[t >> 6] = li;
    __syncthreads();
    if (t == 0) {
        float tot = 0.f;
#pragma unroll
        for (int w = 0; w < 8; ++w) tot += red[w];
        out[0] = tot / 512.0f;
    }
}

// ---------------------------------------------------------------------------
extern "C" void kernel_launch(void* const* d_in, const int* in_sizes, int n_in,
                              void* d_out, int out_size, void* d_ws, size_t ws_size,
                              hipStream_t stream) {
    const int*   nid       = (const int*)d_in[0];
    const float* node_emb  = (const float*)d_in[1];
    const float* wl_w      = (const float*)d_in[2];
    const float* wl_b      = (const float*)d_in[3];
    const float* wr_w      = (const float*)d_in[4];
    const float* wr_b      = (const float*)d_in[5];
    const float* bias_base = (const float*)d_in[6];
    const float* node_bias = (const float*)d_in[7];
    const float* positions = (const float*)d_in[8];
    float* out = (float*)d_out;

    float* ws     = (float*)d_ws;
    float* pe     = ws;                               // 33280
    float* e_all  = pe + 65 * H_;                     // 262144
    float* U0     = e_all + S_ * BS_ * H_;            // 2097152
    float* V0     = U0 + S_ * BS_ * R_ * H_;          // 2097152
    float* A      = V0 + S_ * BS_ * R_ * H_;          // 1048576
    float* cb     = A + S_ * BS_ * R_ * EMB_;         // 4096
    float* proj   = cb + S_ * BS_ * R_;               // 131072
    float* energy = proj + NT_ * R_;                  // 16384
    float* w2f    = energy + NT_;                     // 524288 floats (bf16 x 4096*256)
    float* wrb2   = w2f + (4096 * EMB_) / 2;          // 4096
    float* etgtf  = wrb2 + 4096;                      // 2097152 floats (bf16 x 16384*256)
    float* tgtf   = etgtf + (NT_ * EMB_) / 2;         // 16384 (int)
    float* epart  = tgtf + NT_;                       // 524288
    unsigned short* W2   = (unsigned short*)w2f;
    unsigned short* Etgt = (unsigned short*)etgtf;
    int* tgt_ids = (int*)tgtf;
    // total ~8.9M floats = ~35.5 MB of d_ws

    pe_kernel<<<65, 256, 0, stream>>>(pe);
    e0_kernel<<<8, 256, 0, stream>>>(nid, node_bias, pe, e_all);
    prep_w2<<<4096, 256, 0, stream>>>(wr_w, wr_b, W2, wrb2);
    gather_tgt<<<NT_, 256, 0, stream>>>(nid, node_emb, Etgt, tgt_ids);
    uv0_kernel<<<dim3(32, 16, 2), 256, 0, stream>>>(nid, node_emb, wl_w, wl_b, wr_w, wr_b, U0, V0);
    seq_kernel<<<8, 512, 0, stream>>>(nid, positions, U0, V0, bias_base, node_bias, pe, e_all);
    a_kernel<<<dim3(32, 8), 256, 0, stream>>>(e_all, wl_w, A);
    cb_kernel<<<512, 64, 0, stream>>>(e_all, wl_b, cb);
    proj_kernel<<<512, 256, 0, stream>>>(nid, node_emb, A, cb, proj);
    gemm_big<<<dim3(128, 32), 256, 0, stream>>>(W2, wrb2, Etgt, tgt_ids, proj,
                                                bias_base, node_bias, pe, epart);
    energy_reduce<<<64, 256, 0, stream>>>(epart, energy);
    loss_kernel<<<1, 512, 0, stream>>>(energy, out);
}

// Round 3
// 268.565 us; speedup vs baseline: 4.1973x; 1.3572x over previous
//
#include <hip/hip_runtime.h>
#include <hip/hip_bf16.h>
#include <math.h>

#define S_   64
#define BS_  8
#define NN_  32
#define R_   8
#define H_   512
#define EMB_ 256
#define NT_  16384
#define KT3  2112     // 2048 + 64-pad bias block
#define NS3  33       // K-steps of 64
#define SCALE_ 0.35355339059327373f

typedef __attribute__((ext_vector_type(8))) short bf16x8;
typedef __attribute__((ext_vector_type(4))) float f32x4;
typedef __attribute__((ext_vector_type(4))) int i32x4;

__device__ __forceinline__ float gelu_exact(float x) {
    return 0.5f * x * (1.0f + erff(x * 0.70710678118654752440f));
}
__device__ __forceinline__ unsigned short f2bf(float v) {
    union { float f; unsigned int u; } c; c.f = v;
    unsigned int lsb = (c.u >> 16) & 1;
    c.u += 0x7fff + lsb;
    return (unsigned short)(c.u >> 16);
}
__device__ __forceinline__ int pack2bf(float a, float b) {
    return (int)((unsigned)f2bf(a) | ((unsigned)f2bf(b) << 16));
}
// scale 8 packed bf16 by f32 p, repack bf16
__device__ __forceinline__ i32x4 bf8_scale(i32x4 v, float p) {
    i32x4 out;
#pragma unroll
    for (int q = 0; q < 4; ++q) {
        unsigned u = (unsigned)v[q];
        float lo = __uint_as_float(u << 16);
        float hi = __uint_as_float(u & 0xffff0000u);
        out[q] = pack2bf(lo * p, hi * p);
    }
    return out;
}

// ---------------------------------------------------------------------------
__global__ void pe_kernel(float* __restrict__ pe) {
    int p = blockIdx.x;      // 0..64
    int j = threadIdx.x;     // 0..255
    double ex = (double)(2 * j) / 512.0;
    float divf = (float)exp(ex * 9.210340371976184);
    float ang = (float)p * divf;
    double a = (double)ang;
    pe[p * H_ + 2 * j]     = (float)sin(a);
    pe[p * H_ + 2 * j + 1] = (float)cos(a);
}

// ---------------------------------------------------------------------------
__global__ void e0_kernel(const int* __restrict__ nid,
                          const float* __restrict__ node_bias,
                          const float* __restrict__ pe,
                          float* __restrict__ e_all) {
    int b = blockIdx.x;
    int t = threadIdx.x;
    int src0 = nid[((b * S_ + 0) * NN_ + 0) * 2 + 0];
    for (int h = t; h < H_; h += 256) {
        float g = gelu_exact(node_bias[src0 * H_ + h]);
        e_all[b * H_ + h] = gelu_exact(g + pe[h]);
    }
}

// ---------------------------------------------------------------------------
// W3[h][k], k<2048: bf16(wr_w[(k>>8)*512+h][k&255]); k in [2048,2056): wr_b; else 0
__global__ void prep_w3(const float* __restrict__ wr_w, const float* __restrict__ wr_b,
                        unsigned short* __restrict__ W3) {
    int h = blockIdx.x;
    for (int k = threadIdx.x; k < KT3; k += 256) {
        float v;
        if (k < 2048)       v = wr_w[((k >> 8) * H_ + h) * EMB_ + (k & 255)];
        else if (k < 2056)  v = wr_b[(k - 2048) * H_ + h];
        else                v = 0.f;
        W3[(size_t)h * KT3 + k] = f2bf(v);
    }
}

// ---------------------------------------------------------------------------
// plain bf16 copies of wl_w / wr_w  [4096][256]
__global__ void prep_wlr(const float* __restrict__ wl_w, const float* __restrict__ wr_w,
                         unsigned short* __restrict__ Wl_bf, unsigned short* __restrict__ Wr_bf) {
    int row = blockIdx.x;
    int t = threadIdx.x;
    const float* W = blockIdx.y ? wr_w : wl_w;
    unsigned short* O = blockIdx.y ? Wr_bf : Wl_bf;
    O[(size_t)row * EMB_ + t] = f2bf(W[(size_t)row * EMB_ + t]);
}

// ---------------------------------------------------------------------------
// WlT[r*256+c][h] = bf16(wl_w[r*512+h][c])   (tiled transpose)
__global__ void prep_wlt(const float* __restrict__ wl_w, unsigned short* __restrict__ WlT) {
    __shared__ float tile[64][65];
    int r = blockIdx.x, hb = blockIdx.y, cb = blockIdx.z;
    int t = threadIdx.x;
#pragma unroll
    for (int it = 0; it < 16; ++it) {
        int idx = it * 256 + t;
        int hl = idx >> 6, cl = idx & 63;
        tile[hl][cl] = wl_w[(size_t)(r * H_ + hb * 64 + hl) * EMB_ + cb * 64 + cl];
    }
    __syncthreads();
#pragma unroll
    for (int it = 0; it < 16; ++it) {
        int idx = it * 256 + t;
        int cl = idx >> 6, hl = idx & 63;
        WlT[(size_t)(r * EMB_ + cb * 64 + cl) * H_ + hb * 64 + hl] = f2bf(tile[hl][cl]);
    }
}

// ---------------------------------------------------------------------------
// Etgt[trip][c] bf16 + tgt_ids
__global__ void gather_tgt(const int* __restrict__ nid, const float* __restrict__ node_emb,
                           unsigned short* __restrict__ Etgt, int* __restrict__ tgt_ids) {
    int t = threadIdx.x;
    int trip = blockIdx.x * 32 + (t >> 3);
    int u = t & 7;
    int i = trip >> 8, b = (trip >> 5) & 7, n = trip & 31;
    int id = nid[((b * S_ + i) * NN_ + n) * 2 + 1];
    if (u == 0) tgt_ids[trip] = id;
    const float4* src = (const float4*)(node_emb + (size_t)id * EMB_ + u * 32);
    unsigned short* dst = Etgt + (size_t)trip * EMB_ + u * 32;
#pragma unroll
    for (int q = 0; q < 4; ++q) {
        float4 f0 = src[2 * q], f1 = src[2 * q + 1];
        i32x4 o;
        o[0] = pack2bf(f0.x, f0.y); o[1] = pack2bf(f0.z, f0.w);
        o[2] = pack2bf(f1.x, f1.y); o[3] = pack2bf(f1.z, f1.w);
        *(i32x4*)(dst + q * 8) = o;
    }
}

// ---------------------------------------------------------------------------
// E0[row][c] bf16: row<512 = src0(pair), row>=512 = tgt0(pair)
__global__ void gather_e0(const int* __restrict__ nid, const float* __restrict__ node_emb,
                          unsigned short* __restrict__ E0) {
    int t = threadIdx.x;
    int row = blockIdx.x * 16 + (t >> 4);
    int u = t & 15;
    int uv = row >> 9, pair = row & 511;
    int i = pair >> 3, b = pair & 7;
    int id = nid[((b * S_ + i) * NN_ + 0) * 2 + uv];
    const float4* src = (const float4*)(node_emb + (size_t)id * EMB_ + u * 16);
    unsigned short* dst = E0 + (size_t)row * EMB_ + u * 16;
#pragma unroll
    for (int q = 0; q < 2; ++q) {
        float4 f0 = src[2 * q], f1 = src[2 * q + 1];
        i32x4 o;
        o[0] = pack2bf(f0.x, f0.y); o[1] = pack2bf(f0.z, f0.w);
        o[2] = pack2bf(f1.x, f1.y); o[3] = pack2bf(f1.z, f1.w);
        *(i32x4*)(dst + q * 8) = o;
    }
}

// ---------------------------------------------------------------------------
// Generic C[M][ldC block] = A[M][K](bf16) @ B[N][K](bf16)^T + bias[N]
// 128x128 tile, BK=64, 4 waves (round-2-verified structure)
__global__ __launch_bounds__(256) void gemm_nt(
        const unsigned short* __restrict__ A, const unsigned short* __restrict__ B,
        const float* __restrict__ bias, float* __restrict__ C, int K, int ldC) {
    __shared__ unsigned short Als[128 * 64];
    __shared__ unsigned short Bls[128 * 64];
    int bM = blockIdx.x, bN = blockIdx.y;
    int t = threadIdx.x, w = t >> 6, l = t & 63;
    const unsigned short* Ag = A + (size_t)bM * 128 * K;
    const unsigned short* Bg = B + (size_t)bN * 128 * K;
    int srow = t >> 1, shalf = t & 1;
    size_t sgoff = (size_t)srow * K + shalf * 32;
    int nks = K >> 6;
    f32x4 acc[2][8];
#pragma unroll
    for (int m = 0; m < 2; ++m)
#pragma unroll
        for (int r = 0; r < 8; ++r) acc[m][r] = (f32x4)0.f;
    i32x4 ar[4], br[4];
    {
        const i32x4* ap = (const i32x4*)(Ag + sgoff);
        const i32x4* bp = (const i32x4*)(Bg + sgoff);
#pragma unroll
        for (int q = 0; q < 4; ++q) { ar[q] = ap[q]; br[q] = bp[q]; }
    }
    const int swz = (srow & 7) << 4;
    const int wbase = srow * 128;
    for (int ks = 0; ks < nks; ++ks) {
        __syncthreads();
#pragma unroll
        for (int q = 0; q < 4; ++q) {
            int ba = wbase + ((shalf * 64 + q * 16) ^ swz);
            *(i32x4*)((char*)Als + ba) = ar[q];
            *(i32x4*)((char*)Bls + ba) = br[q];
        }
        __syncthreads();
        if (ks + 1 < nks) {
            const i32x4* ap = (const i32x4*)(Ag + sgoff + (ks + 1) * 64);
            const i32x4* bp = (const i32x4*)(Bg + sgoff + (ks + 1) * 64);
#pragma unroll
            for (int q = 0; q < 4; ++q) { ar[q] = ap[q]; br[q] = bp[q]; }
        }
#pragma unroll
        for (int kk2 = 0; kk2 < 2; ++kk2) {
            bf16x8 af[2], bf[8];
#pragma unroll
            for (int mf = 0; mf < 2; ++mf) {
                int row = w * 32 + mf * 16 + (l & 15);
                int ba = row * 128 + (((kk2 * 64) + ((l >> 4) * 16)) ^ ((row & 7) << 4));
                af[mf] = *(const bf16x8*)((const char*)Als + ba);
            }
#pragma unroll
            for (int r = 0; r < 8; ++r) {
                int row = r * 16 + (l & 15);
                int ba = row * 128 + (((kk2 * 64) + ((l >> 4) * 16)) ^ ((row & 7) << 4));
                bf[r] = *(const bf16x8*)((const char*)Bls + ba);
            }
#pragma unroll
            for (int mf = 0; mf < 2; ++mf)
#pragma unroll
                for (int r = 0; r < 8; ++r)
                    acc[mf][r] = __builtin_amdgcn_mfma_f32_16x16x32_bf16(
                        af[mf], bf[r], acc[mf][r], 0, 0, 0);
        }
    }
    float bv[8];
#pragma unroll
    for (int nf = 0; nf < 8; ++nf)
        bv[nf] = bias ? bias[bN * 128 + nf * 16 + (l & 15)] : 0.f;
#pragma unroll
    for (int mf = 0; mf < 2; ++mf)
#pragma unroll
        for (int nf = 0; nf < 8; ++nf)
#pragma unroll
            for (int reg = 0; reg < 4; ++reg) {
                int row = bM * 128 + w * 32 + mf * 16 + (l >> 4) * 4 + reg;
                int col = bN * 128 + nf * 16 + (l & 15);
                C[(size_t)row * ldC + col] = acc[mf][nf][reg] + bv[nf];
            }
}

// ---------------------------------------------------------------------------
// Sequential chain, 1 block/batch, 512 threads, register-double-buffered.
__global__ __launch_bounds__(512) void seq_kernel(
        const int* __restrict__ nid, const float* __restrict__ positions,
        const float* __restrict__ U0, const float* __restrict__ V0,
        const float* __restrict__ bias_base, const float* __restrict__ node_bias,
        const float* __restrict__ pe, float* __restrict__ e_all,
        unsigned short* __restrict__ e_bf) {
    __shared__ float red8[8][8];
    __shared__ float proj_s[8];
    int b = blockIdx.x;
    int t = threadIdx.x;
    int w = t >> 6, l = t & 63;
    float u[8], v[8], nu[8], nv[8];
    size_t p0 = (size_t)b * 4096;
#pragma unroll
    for (int r = 0; r < 8; ++r) { u[r] = U0[p0 + r * H_ + t]; v[r] = V0[p0 + r * H_ + t]; }
    float ereg = e_all[b * H_ + t];
    float bb = bias_base[t];
    int tgt0 = nid[((b * S_) * NN_) * 2 + 1];
    float nb_cur = node_bias[(size_t)tgt0 * H_ + t];
    float pe_cur = pe[H_ + t];
    float run = 0.f, denom = 0.f;
    for (int i = 0; i < S_; ++i) {
        float nb_n = 0.f, pe_n = 0.f;
        if (i < S_ - 1) {
            size_t pn = (size_t)((i + 1) * BS_ + b) * 4096;
#pragma unroll
            for (int r = 0; r < 8; ++r) { nu[r] = U0[pn + r * H_ + t]; nv[r] = V0[pn + r * H_ + t]; }
            int tgtn = nid[((b * S_ + i + 1) * NN_) * 2 + 1];
            nb_n = node_bias[(size_t)tgtn * H_ + t];
            pe_n = pe[(i + 2) * H_ + t];
        }
        e_all[((size_t)i * BS_ + b) * H_ + t] = ereg;
        e_bf[((size_t)i * BS_ + b) * H_ + t] = f2bf(ereg);
        float pr[8];
#pragma unroll
        for (int r = 0; r < 8; ++r) pr[r] = ereg * u[r];
#pragma unroll
        for (int off = 32; off; off >>= 1)
#pragma unroll
            for (int r = 0; r < 8; ++r) pr[r] += __shfl_down(pr[r], off, 64);
        if (l == 0) {
#pragma unroll
            for (int r = 0; r < 8; ++r) red8[w][r] = pr[r];
        }
        __syncthreads();
        if (t < 8) {
            float s = 0.f;
#pragma unroll
            for (int q = 0; q < 8; ++q) s += red8[q][t];
            proj_s[t] = s;
        }
        __syncthreads();
        float nxt = 0.f;
#pragma unroll
        for (int r = 0; r < 8; ++r) nxt = fmaf(proj_s[r], v[r], nxt);
        float val = fmaf(nxt, SCALE_, bb + nb_cur + pe_cur);
        float o = gelu_exact(val);
        float wi = expf(positions[i]);
        run = fmaf(wi, o, run);
        denom += wi;
        ereg = run / denom;
        if (i < S_ - 1) {
#pragma unroll
            for (int r = 0; r < 8; ++r) { u[r] = nu[r]; v[r] = nv[r]; }
            nb_cur = nb_n; pe_cur = pe_n;
        }
    }
}

// ---------------------------------------------------------------------------
// cb[pair,r] = e . wl_b_r
__global__ void cb_kernel(const float* __restrict__ e_all,
                          const float* __restrict__ wl_b,
                          float* __restrict__ cb) {
    int pair = blockIdx.x;
    int l = threadIdx.x;
    for (int r = 0; r < R_; ++r) {
        float p = 0.f;
#pragma unroll
        for (int k = 0; k < 8; ++k) {
            int h = l + 64 * k;
            p = fmaf(e_all[pair * H_ + h], wl_b[r * H_ + h], p);
        }
#pragma unroll
        for (int off = 32; off; off >>= 1) p += __shfl_down(p, off, 64);
        if (l == 0) cb[pair * R_ + r] = p;
    }
}

// ---------------------------------------------------------------------------
// proj[trip][r] = A2[pair][r*256..]·emb_src[trip] + cb   (8 waves = 8 r's, FIXED)
__global__ __launch_bounds__(512) void proj_kernel(
        const int* __restrict__ nid, const float* __restrict__ node_emb,
        const float* __restrict__ A2, const float* __restrict__ cb,
        float* __restrict__ proj) {
    __shared__ float A_s[R_][EMB_];
    __shared__ float cb_s[R_];
    int pair = blockIdx.x;
    int t = threadIdx.x;
    int w = t >> 6, l = t & 63;
    int i = pair >> 3, b = pair & 7;
#pragma unroll
    for (int q = 0; q < 4; ++q) {
        int idx = q * 512 + t;
        A_s[idx >> 8][idx & 255] = A2[(size_t)pair * 2048 + idx];
    }
    if (t < 8) cb_s[t] = cb[pair * R_ + t];
    __syncthreads();
    float4 a4 = ((const float4*)A_s[w])[l];
    int id = nid[((b * S_ + i) * NN_ + 0) * 2 + 0];
    float4 em = ((const float4*)(node_emb + (size_t)id * EMB_))[l];
    for (int n = 0; n < NN_; ++n) {
        float4 cur = em;
        if (n < NN_ - 1) {
            id = nid[((b * S_ + i) * NN_ + n + 1) * 2 + 0];
            em = ((const float4*)(node_emb + (size_t)id * EMB_))[l];
        }
        float p = cur.x * a4.x + cur.y * a4.y + cur.z * a4.z + cur.w * a4.w;
#pragma unroll
        for (int off = 32; off; off >>= 1) p += __shfl_down(p, off, 64);
        if (l == 0) proj[((size_t)pair * NN_ + n) * R_ + w] = p + cb_s[w];
    }
}

// ---------------------------------------------------------------------------
// Big fused GEMM: nxt = ê @ W3^T, ê built on the fly (proj ⊗ emb), K=2112.
// BM=128 trips, BN=256 h, BK=64; 512 threads, 8 waves (2M x 4N), wave tile 64x64.
// Epilogue: gelu(nxt*SCALE+base+node_bias)² summed over block's 256 h.
__global__ __launch_bounds__(512) void gemm_v3(
        const unsigned short* __restrict__ W3, const unsigned short* __restrict__ Etgt,
        const int* __restrict__ tgt_ids, const float* __restrict__ proj,
        const float* __restrict__ bias_base, const float* __restrict__ pe,
        const float* __restrict__ node_bias, float* __restrict__ epart) {
    __shared__ unsigned short Als[128 * 64];   // 16 KB
    __shared__ unsigned short Bls[256 * 64];   // 32 KB
    __shared__ float proj_s[128 * R_];         // 4 KB
    __shared__ float base_s[256];
    __shared__ float red_s[128 * 4];
    __shared__ int   tgt_s[128];
    int blkM = blockIdx.x;        // 0..127
    int blkN = blockIdx.y;        // 0..1
    int trip0 = blkM * 128;
    int i_blk = blkM >> 1;        // single i per block (128 trips = 4 pairs, 4-aligned)
    int t = threadIdx.x, w = t >> 6, l = t & 63;
    int wm = w >> 2, wn = w & 3;

    proj_s[t] = proj[(size_t)trip0 * R_ + t];
    proj_s[t + 512] = proj[(size_t)trip0 * R_ + t + 512];
    if (t < 256) base_s[t] = bias_base[blkN * 256 + t] + pe[(i_blk + 1) * H_ + blkN * 256 + t];
    if (t < 128) tgt_s[t] = tgt_ids[trip0 + t];
    __syncthreads();

    int srw = t >> 3, sun = t & 7;     // staging row-base / 16B-unit
    f32x4 acc[4][4];
#pragma unroll
    for (int m = 0; m < 4; ++m)
#pragma unroll
        for (int n = 0; n < 4; ++n) acc[m][n] = (f32x4)0.f;

    i32x4 ar[2], br[4];
    // ---- staging helpers (inline) ----
#define A_LOAD(KS)                                                            \
    if ((KS) < 32) {                                                          \
        int c_ = (((KS) & 3) << 6) + (sun << 3);                              \
        _Pragma("unroll")                                                     \
        for (int q = 0; q < 2; ++q)                                           \
            ar[q] = *(const i32x4*)(Etgt + (size_t)(trip0 + q * 64 + srw) * EMB_ + c_); \
    }
#define B_LOAD(KS)                                                            \
    {                                                                         \
        _Pragma("unroll")                                                     \
        for (int q = 0; q < 4; ++q)                                           \
            br[q] = *(const i32x4*)(W3 + (size_t)(blkN * 256 + q * 64 + srw) * KT3 + (KS) * 64 + sun * 8); \
    }
#define STORE(KS)                                                             \
    {                                                                         \
        _Pragma("unroll")                                                     \
        for (int q = 0; q < 2; ++q) {                                         \
            int row = q * 64 + srw;                                           \
            i32x4 aval;                                                       \
            if ((KS) < 32) {                                                  \
                float pf = proj_s[row * R_ + ((KS) >> 2)];                    \
                aval = bf8_scale(ar[q], pf);                                  \
            } else if (sun == 0) {                                            \
                aval[0] = pack2bf(proj_s[row * R_ + 0], proj_s[row * R_ + 1]);\
                aval[1] = pack2bf(proj_s[row * R_ + 2], proj_s[row * R_ + 3]);\
                aval[2] = pack2bf(proj_s[row * R_ + 4], proj_s[row * R_ + 5]);\
                aval[3] = pack2bf(proj_s[row * R_ + 6], proj_s[row * R_ + 7]);\
            } else { aval[0] = 0; aval[1] = 0; aval[2] = 0; aval[3] = 0; }    \
            int ba = row * 128 + ((sun * 16) ^ ((row & 7) << 4));             \
            *(i32x4*)((char*)Als + ba) = aval;                                \
        }                                                                     \
        _Pragma("unroll")                                                     \
        for (int q = 0; q < 4; ++q) {                                         \
            int row = q * 64 + srw;                                           \
            int ba = row * 128 + ((sun * 16) ^ ((row & 7) << 4));             \
            *(i32x4*)((char*)Bls + ba) = br[q];                               \
        }                                                                     \
    }

    A_LOAD(0); B_LOAD(0); STORE(0);
    for (int ks = 0; ks < NS3; ++ks) {
        __syncthreads();
        if (ks + 1 < NS3) { A_LOAD(ks + 1); B_LOAD(ks + 1); }
#pragma unroll
        for (int kk2 = 0; kk2 < 2; ++kk2) {
            bf16x8 af[4], bf[4];
            int kb = kk2 * 64 + ((l >> 4) << 4);
#pragma unroll
            for (int mf = 0; mf < 4; ++mf) {
                int row = wm * 64 + mf * 16 + (l & 15);
                af[mf] = *(const bf16x8*)((const char*)Als + row * 128 + (kb ^ ((row & 7) << 4)));
            }
#pragma unroll
            for (int nf = 0; nf < 4; ++nf) {
                int row = wn * 64 + nf * 16 + (l & 15);
                bf[nf] = *(const bf16x8*)((const char*)Bls + row * 128 + (kb ^ ((row & 7) << 4)));
            }
#pragma unroll
            for (int mf = 0; mf < 4; ++mf)
#pragma unroll
                for (int nf = 0; nf < 4; ++nf)
                    acc[mf][nf] = __builtin_amdgcn_mfma_f32_16x16x32_bf16(
                        af[mf], bf[nf], acc[mf][nf], 0, 0, 0);
        }
        __syncthreads();
        if (ks + 1 < NS3) STORE(ks + 1);
    }
#undef A_LOAD
#undef B_LOAD
#undef STORE

    int hl = l & 15, lq = l >> 4;
#pragma unroll
    for (int mf = 0; mf < 4; ++mf)
#pragma unroll
        for (int reg = 0; reg < 4; ++reg) {
            int tl = wm * 64 + mf * 16 + lq * 4 + reg;
            int tgt = tgt_s[tl];
            float s = 0.f;
#pragma unroll
            for (int nf = 0; nf < 4; ++nf) {
                int hloc = wn * 64 + nf * 16 + hl;
                int h = blkN * 256 + hloc;
                float val = fmaf(acc[mf][nf][reg], SCALE_,
                                 base_s[hloc] + node_bias[(size_t)tgt * H_ + h]);
                float o = gelu_exact(val);
                s = fmaf(o, o, s);
            }
            s += __shfl_xor(s, 1, 64);
            s += __shfl_xor(s, 2, 64);
            s += __shfl_xor(s, 4, 64);
            s += __shfl_xor(s, 8, 64);
            if (hl == 0) red_s[tl * 4 + wn] = s;
        }
    __syncthreads();
    if (t < 128) {
        float s = red_s[t * 4] + red_s[t * 4 + 1] + red_s[t * 4 + 2] + red_s[t * 4 + 3];
        epart[(size_t)(trip0 + t) * 2 + blkN] = s;
    }
}

// ---------------------------------------------------------------------------
__global__ void energy_fin(const float* __restrict__ epart, float* __restrict__ energy) {
    int idx = blockIdx.x * 256 + threadIdx.x;
    energy[idx] = sqrtf(epart[idx * 2] + epart[idx * 2 + 1]);
}

// ---------------------------------------------------------------------------
__global__ void loss_kernel(const float* __restrict__ energy, float* __restrict__ out) {
    __shared__ float red[8];
    int t = threadIdx.x;  // 512 pairs
    float en[NN_];
    float mx = -1e30f;
#pragma unroll
    for (int n = 0; n < NN_; ++n) {
        en[n] = energy[t * NN_ + n];
        mx = fmaxf(mx, en[n]);
    }
    float s = 0.f;
#pragma unroll
    for (int n = 0; n < NN_; ++n) s += expf(en[n] - mx);
    float li = logf(s) + mx - en[0];
#pragma unroll
    for (int off = 32; off; off >>= 1) li += __shfl_down(li, off, 64);
    if ((t & 63) == 0) red[t >> 6] = li;
    __syncthreads();
    if (t == 0) {
        float tot = 0.f;
#pragma unroll
        for (int w = 0; w < 8; ++w) tot += red[w];
        out[0] = tot / 512.0f;
    }
}

// ---------------------------------------------------------------------------
extern "C" void kernel_launch(void* const* d_in, const int* in_sizes, int n_in,
                              void* d_out, int out_size, void* d_ws, size_t ws_size,
                              hipStream_t stream) {
    const int*   nid       = (const int*)d_in[0];
    const float* node_emb  = (const float*)d_in[1];
    const float* wl_w      = (const float*)d_in[2];
    const float* wl_b      = (const float*)d_in[3];
    const float* wr_w      = (const float*)d_in[4];
    const float* wr_b      = (const float*)d_in[5];
    const float* bias_base = (const float*)d_in[6];
    const float* node_bias = (const float*)d_in[7];
    const float* positions = (const float*)d_in[8];
    float* out = (float*)d_out;

    float* ws      = (float*)d_ws;
    float* pe      = ws;                        // 33280
    float* e_all   = pe + 65 * H_;              // 262144
    float* U0      = e_all + 512 * H_;          // 2097152
    float* V0      = U0 + 512 * 4096;           // 2097152
    float* A2      = V0 + 512 * 4096;           // 1048576
    float* cb      = A2 + 512 * 2048;           // 4096
    float* proj    = cb + 4096;                 // 131072
    float* energy  = proj + NT_ * R_;           // 16384
    float* epart   = energy + NT_;              // 32768
    unsigned short* e_bf  = (unsigned short*)(epart + 2 * NT_);   // 262144 sh
    unsigned short* W3    = e_bf + 512 * H_;                      // 512*2112 sh
    unsigned short* Wl_bf = W3 + 512 * KT3;                       // 1048576 sh
    unsigned short* Wr_bf = Wl_bf + 4096 * EMB_;                  // 1048576 sh
    unsigned short* WlT   = Wr_bf + 4096 * EMB_;                  // 1048576 sh
    unsigned short* E0    = WlT + 2048 * H_;                      // 262144 sh
    unsigned short* Etgt  = E0 + 1024 * EMB_;                     // 4194304 sh
    int* tgt_ids = (int*)(Etgt + (size_t)NT_ * EMB_);             // 16384

    pe_kernel<<<65, 256, 0, stream>>>(pe);
    e0_kernel<<<8, 256, 0, stream>>>(nid, node_bias, pe, e_all);
    prep_w3<<<512, 256, 0, stream>>>(wr_w, wr_b, W3);
    prep_wlr<<<dim3(4096, 2), 256, 0, stream>>>(wl_w, wr_w, Wl_bf, Wr_bf);
    prep_wlt<<<dim3(8, 8, 4), 256, 0, stream>>>(wl_w, WlT);
    gather_tgt<<<512, 256, 0, stream>>>(nid, node_emb, Etgt, tgt_ids);
    gather_e0<<<64, 256, 0, stream>>>(nid, node_emb, E0);
    gemm_nt<<<dim3(4, 32), 256, 0, stream>>>(E0, Wl_bf, wl_b, U0, 256, 4096);
    gemm_nt<<<dim3(4, 32), 256, 0, stream>>>(E0 + 512 * EMB_, Wr_bf, wr_b, V0, 256, 4096);
    seq_kernel<<<8, 512, 0, stream>>>(nid, positions, U0, V0, bias_base, node_bias, pe, e_all, e_bf);
    cb_kernel<<<512, 64, 0, stream>>>(e_all, wl_b, cb);
    gemm_nt<<<dim3(4, 16), 256, 0, stream>>>(e_bf, WlT, nullptr, A2, 512, 2048);
    proj_kernel<<<512, 512, 0, stream>>>(nid, node_emb, A2, cb, proj);
    gemm_v3<<<dim3(128, 2), 512, 0, stream>>>(W3, Etgt, tgt_ids, proj, bias_base, pe, node_bias, epart);
    energy_fin<<<64, 256, 0, stream>>>(epart, energy);
    loss_kernel<<<1, 512, 0, stream>>>(energy, out);
}

// Round 4
// 204.748 us; speedup vs baseline: 5.5056x; 1.3117x over previous
//
#include <hip/hip_runtime.h>
#include <hip/hip_bf16.h>
#include <math.h>

#define S_   64
#define BS_  8
#define NN_  32
#define R_   8
#define H_   512
#define EMB_ 256
#define NT_  16384
#define KT3  2112     // 2048 + 64-pad bias block
#define NS3  33       // K-steps of 64
#define SCALE_ 0.35355339059327373f

typedef __attribute__((ext_vector_type(8))) short bf16x8;
typedef __attribute__((ext_vector_type(4))) float f32x4;
typedef __attribute__((ext_vector_type(4))) int i32x4;

__device__ __forceinline__ float gelu_exact(float x) {
    return 0.5f * x * (1.0f + erff(x * 0.70710678118654752440f));
}
// tanh-form gelu (max err ~1e-3 vs exact in |x|<2). Used ONLY on the e-chain
// (cache path), whose loss contribution flows through the rank-8 term that
// already tolerates bf16 rounding. Energy path keeps gelu_exact.
__device__ __forceinline__ float gelu_fast(float x) {
    float inner = 0.7978845608028654f * fmaf(0.044715f * x, x * x, x);
    float e = __expf(2.0f * inner);
    return x * (1.0f - __builtin_amdgcn_rcpf(e + 1.0f));  // x*e/(e+1), inf-safe
}
__device__ __forceinline__ unsigned short f2bf(float v) {
    union { float f; unsigned int u; } c; c.f = v;
    unsigned int lsb = (c.u >> 16) & 1;
    c.u += 0x7fff + lsb;
    return (unsigned short)(c.u >> 16);
}
__device__ __forceinline__ int pack2bf(float a, float b) {
    return (int)((unsigned)f2bf(a) | ((unsigned)f2bf(b) << 16));
}
__device__ __forceinline__ i32x4 bf8_scale(i32x4 v, float p) {
    i32x4 out;
#pragma unroll
    for (int q = 0; q < 4; ++q) {
        unsigned u = (unsigned)v[q];
        float lo = __uint_as_float(u << 16);
        float hi = __uint_as_float(u & 0xffff0000u);
        out[q] = pack2bf(lo * p, hi * p);
    }
    return out;
}

// ---------------------------------------------------------------------------
// prep_all: pe table, e0, bf16 copies of wl_w/wr_w, E0 gather. 4233 blocks.
__global__ __launch_bounds__(256) void prep_all(
        const int* __restrict__ nid, const float* __restrict__ node_emb,
        const float* __restrict__ wl_w, const float* __restrict__ wr_w,
        const float* __restrict__ node_bias,
        float* __restrict__ pe, float* __restrict__ e_all,
        unsigned short* __restrict__ Wl_bf, unsigned short* __restrict__ Wr_bf,
        unsigned short* __restrict__ E0) {
    int blk = blockIdx.x, t = threadIdx.x;
    if (blk < 4096) {
        Wl_bf[(size_t)blk * 256 + t] = f2bf(wl_w[(size_t)blk * 256 + t]);
        Wr_bf[(size_t)blk * 256 + t] = f2bf(wr_w[(size_t)blk * 256 + t]);
    } else if (blk < 4161) {
        int p = blk - 4096, j = t;
        double ex = (double)(2 * j) / 512.0;
        float divf = (float)exp(ex * 9.210340371976184);
        float ang = (float)p * divf;
        double a = (double)ang;
        pe[p * H_ + 2 * j]     = (float)sin(a);
        pe[p * H_ + 2 * j + 1] = (float)cos(a);
    } else if (blk < 4169) {
        int b = blk - 4161;
        int src0 = nid[((b * S_ + 0) * NN_ + 0) * 2 + 0];
        for (int h = t; h < H_; h += 256) {
            float pe0 = (h & 1) ? 1.0f : 0.0f;   // pe[0] = [sin0,cos0,...]
            float g = gelu_fast(node_bias[(size_t)src0 * H_ + h]);
            e_all[b * H_ + h] = gelu_fast(g + pe0);
        }
    } else {
        int blk0 = blk - 4169;                    // 64 blocks, E0 gather
        int row = blk0 * 16 + (t >> 4);
        int u = t & 15;
        int uv = row >> 9, pair = row & 511;
        int i = pair >> 3, b = pair & 7;
        int id = nid[((b * S_ + i) * NN_ + 0) * 2 + uv];
        const float4* src = (const float4*)(node_emb + (size_t)id * EMB_ + u * 16);
        unsigned short* dst = E0 + (size_t)row * EMB_ + u * 16;
#pragma unroll
        for (int q = 0; q < 2; ++q) {
            float4 f0 = src[2 * q], f1 = src[2 * q + 1];
            i32x4 o;
            o[0] = pack2bf(f0.x, f0.y); o[1] = pack2bf(f0.z, f0.w);
            o[2] = pack2bf(f1.x, f1.y); o[3] = pack2bf(f1.z, f1.w);
            *(i32x4*)(dst + q * 8) = o;
        }
    }
}

// ---------------------------------------------------------------------------
// Dual-tensor GEMM C = A@B^T (+bias), 128x128 tile, BK=64, 4 waves.
// blockIdx.z picks parameter set (for fused U0/V0 launch).
__global__ __launch_bounds__(256) void gemm_nt(
        const unsigned short* __restrict__ A0, const unsigned short* __restrict__ B0,
        const float* __restrict__ bias0, float* __restrict__ C0,
        const unsigned short* __restrict__ A1, const unsigned short* __restrict__ B1,
        const float* __restrict__ bias1, float* __restrict__ C1,
        int K, int ldC) {
    const unsigned short* A = blockIdx.z ? A1 : A0;
    const unsigned short* B = blockIdx.z ? B1 : B0;
    const float* bias = blockIdx.z ? bias1 : bias0;
    float* C = blockIdx.z ? C1 : C0;
    __shared__ unsigned short Als[128 * 64];
    __shared__ unsigned short Bls[128 * 64];
    int bM = blockIdx.x, bN = blockIdx.y;
    int t = threadIdx.x, w = t >> 6, l = t & 63;
    const unsigned short* Ag = A + (size_t)bM * 128 * K;
    const unsigned short* Bg = B + (size_t)bN * 128 * K;
    int srow = t >> 1, shalf = t & 1;
    size_t sgoff = (size_t)srow * K + shalf * 32;
    int nks = K >> 6;
    f32x4 acc[2][8];
#pragma unroll
    for (int m = 0; m < 2; ++m)
#pragma unroll
        for (int r = 0; r < 8; ++r) acc[m][r] = (f32x4)0.f;
    i32x4 ar[4], br[4];
    {
        const i32x4* ap = (const i32x4*)(Ag + sgoff);
        const i32x4* bp = (const i32x4*)(Bg + sgoff);
#pragma unroll
        for (int q = 0; q < 4; ++q) { ar[q] = ap[q]; br[q] = bp[q]; }
    }
    const int swz = (srow & 7) << 4;
    const int wbase = srow * 128;
    for (int ks = 0; ks < nks; ++ks) {
        __syncthreads();
#pragma unroll
        for (int q = 0; q < 4; ++q) {
            int ba = wbase + ((shalf * 64 + q * 16) ^ swz);
            *(i32x4*)((char*)Als + ba) = ar[q];
            *(i32x4*)((char*)Bls + ba) = br[q];
        }
        __syncthreads();
        if (ks + 1 < nks) {
            const i32x4* ap = (const i32x4*)(Ag + sgoff + (ks + 1) * 64);
            const i32x4* bp = (const i32x4*)(Bg + sgoff + (ks + 1) * 64);
#pragma unroll
            for (int q = 0; q < 4; ++q) { ar[q] = ap[q]; br[q] = bp[q]; }
        }
#pragma unroll
        for (int kk2 = 0; kk2 < 2; ++kk2) {
            bf16x8 af[2], bf[8];
#pragma unroll
            for (int mf = 0; mf < 2; ++mf) {
                int row = w * 32 + mf * 16 + (l & 15);
                int ba = row * 128 + (((kk2 * 64) + ((l >> 4) * 16)) ^ ((row & 7) << 4));
                af[mf] = *(const bf16x8*)((const char*)Als + ba);
            }
#pragma unroll
            for (int r = 0; r < 8; ++r) {
                int row = r * 16 + (l & 15);
                int ba = row * 128 + (((kk2 * 64) + ((l >> 4) * 16)) ^ ((row & 7) << 4));
                bf[r] = *(const bf16x8*)((const char*)Bls + ba);
            }
#pragma unroll
            for (int mf = 0; mf < 2; ++mf)
#pragma unroll
                for (int r = 0; r < 8; ++r)
                    acc[mf][r] = __builtin_amdgcn_mfma_f32_16x16x32_bf16(
                        af[mf], bf[r], acc[mf][r], 0, 0, 0);
        }
    }
    float bv[8];
#pragma unroll
    for (int nf = 0; nf < 8; ++nf)
        bv[nf] = bias ? bias[bN * 128 + nf * 16 + (l & 15)] : 0.f;
#pragma unroll
    for (int mf = 0; mf < 2; ++mf)
#pragma unroll
        for (int nf = 0; nf < 8; ++nf)
#pragma unroll
            for (int reg = 0; reg < 4; ++reg) {
                int row = bM * 128 + w * 32 + mf * 16 + (l >> 4) * 4 + reg;
                int col = bN * 128 + nf * 16 + (l & 15);
                C[(size_t)row * ldC + col] = acc[mf][nf][reg] + bv[nf];
            }
}

// ---------------------------------------------------------------------------
// seq_prep: blocks 0-7 = single-wave sequential chains (latency-critical);
// blocks 8+ = independent prep (W3, WlT, Etgt) filling the idle CUs.
__global__ __launch_bounds__(256, 1) void seq_prep(
        const int* __restrict__ nid, const float* __restrict__ positions,
        const float* __restrict__ U0, const float* __restrict__ V0,
        const float* __restrict__ bias_base, const float* __restrict__ node_bias,
        const float* __restrict__ pe, float* __restrict__ e_all,
        unsigned short* __restrict__ e_bf,
        const float* __restrict__ wr_w, const float* __restrict__ wr_b,
        unsigned short* __restrict__ W3,
        const float* __restrict__ wl_w, unsigned short* __restrict__ WlT,
        const float* __restrict__ node_emb,
        unsigned short* __restrict__ Etgt, int* __restrict__ tgt_ids) {
    int blk = blockIdx.x;
    int t = threadIdx.x;
    if (blk < 8) {
        // ------------ sequential chain, ONE wave, no barriers ------------
        if (t >= 64) return;
        __shared__ float w_s[64], inv_s[64];
        int b = blk, l = t;
        // per-step weights + inverse prefix denominators (off critical path)
        float wv = __expf(positions[l]);
        float ps = wv;
#pragma unroll
        for (int d = 1; d < 64; d <<= 1) {
            float o = __shfl_up(ps, d, 64);
            if (l >= d) ps += o;
        }
        w_s[l] = wv;
        inv_s[l] = 1.0f / ps;

        float uA[8][8], uB[8][8];
        float nbA[8], nbB[8], peA[8], peB[8], bb[8], er[8], run[8];
        {
            size_t b0 = (size_t)b * 4096 + l * 8;
#pragma unroll
            for (int r = 0; r < 8; ++r) {
                float4 a0 = *(const float4*)&U0[b0 + r * H_];
                float4 a1 = *(const float4*)&U0[b0 + r * H_ + 4];
                uA[r][0] = a0.x; uA[r][1] = a0.y; uA[r][2] = a0.z; uA[r][3] = a0.w;
                uA[r][4] = a1.x; uA[r][5] = a1.y; uA[r][6] = a1.z; uA[r][7] = a1.w;
            }
            int tgt0 = nid[((b * S_) * NN_) * 2 + 1];
            float4 n0 = *(const float4*)&node_bias[(size_t)tgt0 * H_ + l * 8];
            float4 n1 = *(const float4*)&node_bias[(size_t)tgt0 * H_ + l * 8 + 4];
            nbA[0] = n0.x; nbA[1] = n0.y; nbA[2] = n0.z; nbA[3] = n0.w;
            nbA[4] = n1.x; nbA[5] = n1.y; nbA[6] = n1.z; nbA[7] = n1.w;
            float4 p0 = *(const float4*)&pe[H_ + l * 8];
            float4 p1 = *(const float4*)&pe[H_ + l * 8 + 4];
            peA[0] = p0.x; peA[1] = p0.y; peA[2] = p0.z; peA[3] = p0.w;
            peA[4] = p1.x; peA[5] = p1.y; peA[6] = p1.z; peA[7] = p1.w;
            float4 c0 = *(const float4*)&bias_base[l * 8];
            float4 c1 = *(const float4*)&bias_base[l * 8 + 4];
            bb[0] = c0.x; bb[1] = c0.y; bb[2] = c0.z; bb[3] = c0.w;
            bb[4] = c1.x; bb[5] = c1.y; bb[6] = c1.z; bb[7] = c1.w;
            float4 e0v = *(const float4*)&e_all[b * H_ + l * 8];
            float4 e1v = *(const float4*)&e_all[b * H_ + l * 8 + 4];
            er[0] = e0v.x; er[1] = e0v.y; er[2] = e0v.z; er[3] = e0v.w;
            er[4] = e1v.x; er[5] = e1v.y; er[6] = e1v.z; er[7] = e1v.w;
#pragma unroll
            for (int j = 0; j < 8; ++j) run[j] = 0.f;
        }

        auto step = [&](float (&uc)[8][8], float (&un)[8][8],
                        float (&nbc)[8], float (&nbn)[8],
                        float (&pc)[8], float (&pn)[8], int i) {
            // prefetch next step's U row / node_bias / pe (independent of chain)
            if (i + 1 < S_) {
                size_t bn = ((size_t)(i + 1) * BS_ + b) * 4096 + l * 8;
#pragma unroll
                for (int r = 0; r < 8; ++r) {
                    float4 a0 = *(const float4*)&U0[bn + r * H_];
                    float4 a1 = *(const float4*)&U0[bn + r * H_ + 4];
                    un[r][0] = a0.x; un[r][1] = a0.y; un[r][2] = a0.z; un[r][3] = a0.w;
                    un[r][4] = a1.x; un[r][5] = a1.y; un[r][6] = a1.z; un[r][7] = a1.w;
                }
                int tgtn = nid[((b * S_ + i + 1) * NN_) * 2 + 1];
                float4 n0 = *(const float4*)&node_bias[(size_t)tgtn * H_ + l * 8];
                float4 n1 = *(const float4*)&node_bias[(size_t)tgtn * H_ + l * 8 + 4];
                nbn[0] = n0.x; nbn[1] = n0.y; nbn[2] = n0.z; nbn[3] = n0.w;
                nbn[4] = n1.x; nbn[5] = n1.y; nbn[6] = n1.z; nbn[7] = n1.w;
                float4 p0 = *(const float4*)&pe[(i + 2) * H_ + l * 8];
                float4 p1 = *(const float4*)&pe[(i + 2) * H_ + l * 8 + 4];
                pn[0] = p0.x; pn[1] = p0.y; pn[2] = p0.z; pn[3] = p0.w;
                pn[4] = p1.x; pn[5] = p1.y; pn[6] = p1.z; pn[7] = p1.w;
            }
            // V for the current step (consumed ~350cy later -> latency hidden)
            float v[8][8];
            size_t bc = ((size_t)i * BS_ + b) * 4096 + l * 8;
#pragma unroll
            for (int r = 0; r < 8; ++r) {
                float4 a0 = *(const float4*)&V0[bc + r * H_];
                float4 a1 = *(const float4*)&V0[bc + r * H_ + 4];
                v[r][0] = a0.x; v[r][1] = a0.y; v[r][2] = a0.z; v[r][3] = a0.w;
                v[r][4] = a1.x; v[r][5] = a1.y; v[r][6] = a1.z; v[r][7] = a1.w;
            }
            // store e_i (off chain)
            size_t eo = ((size_t)i * BS_ + b) * H_ + l * 8;
            *(float4*)&e_all[eo]     = make_float4(er[0], er[1], er[2], er[3]);
            *(float4*)&e_all[eo + 4] = make_float4(er[4], er[5], er[6], er[7]);
            i32x4 ep;
            ep[0] = pack2bf(er[0], er[1]); ep[1] = pack2bf(er[2], er[3]);
            ep[2] = pack2bf(er[4], er[5]); ep[3] = pack2bf(er[6], er[7]);
            *(i32x4*)&e_bf[eo] = ep;
            // proj[r] = e . U_r  (local dots + butterfly)
            float pr[8];
#pragma unroll
            for (int r = 0; r < 8; ++r) {
                float p = er[0] * uc[r][0];
#pragma unroll
                for (int j = 1; j < 8; ++j) p = fmaf(er[j], uc[r][j], p);
                pr[r] = p;
            }
#pragma unroll
            for (int mask = 1; mask < 64; mask <<= 1)
#pragma unroll
                for (int r = 0; r < 8; ++r) pr[r] += __shfl_xor(pr[r], mask, 64);
            // nxt, gelu, running softmax-mean
            float wi = w_s[i], inv = inv_s[i];
#pragma unroll
            for (int j = 0; j < 8; ++j) {
                float nx = pr[0] * v[0][j];
#pragma unroll
                for (int r = 1; r < 8; ++r) nx = fmaf(pr[r], v[r][j], nx);
                float val = fmaf(nx, SCALE_, bb[j] + nbc[j] + pc[j]);
                float o = gelu_fast(val);
                run[j] = fmaf(wi, o, run[j]);
                er[j] = run[j] * inv;
            }
        };
        for (int i = 0; i < S_; i += 2) {
            step(uA, uB, nbA, nbB, peA, peB, i);
            step(uB, uA, nbB, nbA, peB, peA, i + 1);
        }
    } else if (blk < 8 + 512) {
        // ------------ W3 prep ------------
        int h = blk - 8;
        for (int k = t; k < KT3; k += 256) {
            float v;
            if (k < 2048)       v = wr_w[(size_t)((k >> 8) * H_ + h) * EMB_ + (k & 255)];
            else if (k < 2056)  v = wr_b[(size_t)(k - 2048) * H_ + h];
            else                v = 0.f;
            W3[(size_t)h * KT3 + k] = f2bf(v);
        }
    } else if (blk < 8 + 512 + 256) {
        // ------------ WlT transpose ------------
        __shared__ float tile[64][65];
        int b2 = blk - 520;
        int r = b2 >> 5, hb = (b2 >> 2) & 7, cb = b2 & 3;
#pragma unroll
        for (int it = 0; it < 16; ++it) {
            int idx = it * 256 + t;
            int hl = idx >> 6, cl = idx & 63;
            tile[hl][cl] = wl_w[(size_t)(r * H_ + hb * 64 + hl) * EMB_ + cb * 64 + cl];
        }
        __syncthreads();
#pragma unroll
        for (int it = 0; it < 16; ++it) {
            int idx = it * 256 + t;
            int cl = idx >> 6, hl = idx & 63;
            WlT[(size_t)(r * EMB_ + cb * 64 + cl) * H_ + hb * 64 + hl] = f2bf(tile[hl][cl]);
        }
    } else {
        // ------------ Etgt gather ------------
        int b3 = blk - 776;
        int trip = b3 * 32 + (t >> 3);
        int u = t & 7;
        int i = trip >> 8, b = (trip >> 5) & 7, n = trip & 31;
        int id = nid[((b * S_ + i) * NN_ + n) * 2 + 1];
        if (u == 0) tgt_ids[trip] = id;
        const float4* src = (const float4*)(node_emb + (size_t)id * EMB_ + u * 32);
        unsigned short* dst = Etgt + (size_t)trip * EMB_ + u * 32;
#pragma unroll
        for (int q = 0; q < 4; ++q) {
            float4 f0 = src[2 * q], f1 = src[2 * q + 1];
            i32x4 o;
            o[0] = pack2bf(f0.x, f0.y); o[1] = pack2bf(f0.z, f0.w);
            o[2] = pack2bf(f1.x, f1.y); o[3] = pack2bf(f1.z, f1.w);
            *(i32x4*)(dst + q * 8) = o;
        }
    }
}

// ---------------------------------------------------------------------------
// proj (with cb folded): proj[trip][r] = A2[pair][r*256..]·emb_src + e·wl_b_r
__global__ __launch_bounds__(512) void proj_kernel(
        const int* __restrict__ nid, const float* __restrict__ node_emb,
        const float* __restrict__ A2, const float* __restrict__ e_all,
        const float* __restrict__ wl_b, float* __restrict__ proj) {
    __shared__ float A_s[R_][EMB_];
    __shared__ float cb_s[R_];
    int pair = blockIdx.x;
    int t = threadIdx.x;
    int w = t >> 6, l = t & 63;
    int i = pair >> 3, b = pair & 7;
#pragma unroll
    for (int q = 0; q < 4; ++q) {
        int idx = q * 512 + t;
        A_s[idx >> 8][idx & 255] = A2[(size_t)pair * 2048 + idx];
    }
    {   // cb[w] = e . wl_b_w
        float p = 0.f;
#pragma unroll
        for (int k = 0; k < 8; ++k) {
            int h = l + 64 * k;
            p = fmaf(e_all[(size_t)pair * H_ + h], wl_b[(size_t)w * H_ + h], p);
        }
#pragma unroll
        for (int mask = 1; mask < 64; mask <<= 1) p += __shfl_xor(p, mask, 64);
        if (l == 0) cb_s[w] = p;
    }
    __syncthreads();
    float4 a4 = ((const float4*)A_s[w])[l];
    int id = nid[((b * S_ + i) * NN_ + 0) * 2 + 0];
    float4 em = ((const float4*)(node_emb + (size_t)id * EMB_))[l];
    for (int n = 0; n < NN_; ++n) {
        float4 cur = em;
        if (n < NN_ - 1) {
            id = nid[((b * S_ + i) * NN_ + n + 1) * 2 + 0];
            em = ((const float4*)(node_emb + (size_t)id * EMB_))[l];
        }
        float p = cur.x * a4.x + cur.y * a4.y + cur.z * a4.z + cur.w * a4.w;
#pragma unroll
        for (int off = 32; off; off >>= 1) p += __shfl_down(p, off, 64);
        if (l == 0) proj[((size_t)pair * NN_ + n) * R_ + w] = p + cb_s[w];
    }
}

// ---------------------------------------------------------------------------
// Big fused GEMM: nxt = ê @ W3^T, ê built on the fly (proj ⊗ emb), K=2112.
__global__ __launch_bounds__(512) void gemm_v3(
        const unsigned short* __restrict__ W3, const unsigned short* __restrict__ Etgt,
        const int* __restrict__ tgt_ids, const float* __restrict__ proj,
        const float* __restrict__ bias_base, const float* __restrict__ pe,
        const float* __restrict__ node_bias, float* __restrict__ epart) {
    __shared__ unsigned short Als[128 * 64];
    __shared__ unsigned short Bls[256 * 64];
    __shared__ float proj_s[128 * R_];
    __shared__ float base_s[256];
    __shared__ float red_s[128 * 4];
    __shared__ int   tgt_s[128];
    int blkM = blockIdx.x;
    int blkN = blockIdx.y;
    int trip0 = blkM * 128;
    int i_blk = blkM >> 1;
    int t = threadIdx.x, w = t >> 6, l = t & 63;
    int wm = w >> 2, wn = w & 3;

    proj_s[t] = proj[(size_t)trip0 * R_ + t];
    proj_s[t + 512] = proj[(size_t)trip0 * R_ + t + 512];
    if (t < 256) base_s[t] = bias_base[blkN * 256 + t] + pe[(i_blk + 1) * H_ + blkN * 256 + t];
    if (t < 128) tgt_s[t] = tgt_ids[trip0 + t];
    __syncthreads();

    int srw = t >> 3, sun = t & 7;
    f32x4 acc[4][4];
#pragma unroll
    for (int m = 0; m < 4; ++m)
#pragma unroll
        for (int n = 0; n < 4; ++n) acc[m][n] = (f32x4)0.f;

    i32x4 ar[2], br[4];
#define A_LOAD(KS)                                                            \
    if ((KS) < 32) {                                                          \
        int c_ = (((KS) & 3) << 6) + (sun << 3);                              \
        _Pragma("unroll")                                                     \
        for (int q = 0; q < 2; ++q)                                           \
            ar[q] = *(const i32x4*)(Etgt + (size_t)(trip0 + q * 64 + srw) * EMB_ + c_); \
    }
#define B_LOAD(KS)                                                            \
    {                                                                         \
        _Pragma("unroll")                                                     \
        for (int q = 0; q < 4; ++q)                                           \
            br[q] = *(const i32x4*)(W3 + (size_t)(blkN * 256 + q * 64 + srw) * KT3 + (KS) * 64 + sun * 8); \
    }
#define STORE(KS)                                                             \
    {                                                                         \
        _Pragma("unroll")                                                     \
        for (int q = 0; q < 2; ++q) {                                         \
            int row = q * 64 + srw;                                           \
            i32x4 aval;                                                       \
            if ((KS) < 32) {                                                  \
                float pf = proj_s[row * R_ + ((KS) >> 2)];                    \
                aval = bf8_scale(ar[q], pf);                                  \
            } else if (sun == 0) {                                            \
                aval[0] = pack2bf(proj_s[row * R_ + 0], proj_s[row * R_ + 1]);\
                aval[1] = pack2bf(proj_s[row * R_ + 2], proj_s[row * R_ + 3]);\
                aval[2] = pack2bf(proj_s[row * R_ + 4], proj_s[row * R_ + 5]);\
                aval[3] = pack2bf(proj_s[row * R_ + 6], proj_s[row * R_ + 7]);\
            } else { aval[0] = 0; aval[1] = 0; aval[2] = 0; aval[3] = 0; }    \
            int ba = row * 128 + ((sun * 16) ^ ((row & 7) << 4));             \
            *(i32x4*)((char*)Als + ba) = aval;                                \
        }                                                                     \
        _Pragma("unroll")                                                     \
        for (int q = 0; q < 4; ++q) {                                         \
            int row = q * 64 + srw;                                           \
            int ba = row * 128 + ((sun * 16) ^ ((row & 7) << 4));             \
            *(i32x4*)((char*)Bls + ba) = br[q];                               \
        }                                                                     \
    }

    A_LOAD(0); B_LOAD(0); STORE(0);
    for (int ks = 0; ks < NS3; ++ks) {
        __syncthreads();
        if (ks + 1 < NS3) { A_LOAD(ks + 1); B_LOAD(ks + 1); }
#pragma unroll
        for (int kk2 = 0; kk2 < 2; ++kk2) {
            bf16x8 af[4], bf[4];
            int kb = kk2 * 64 + ((l >> 4) << 4);
#pragma unroll
            for (int mf = 0; mf < 4; ++mf) {
                int row = wm * 64 + mf * 16 + (l & 15);
                af[mf] = *(const bf16x8*)((const char*)Als + row * 128 + (kb ^ ((row & 7) << 4)));
            }
#pragma unroll
            for (int nf = 0; nf < 4; ++nf) {
                int row = wn * 64 + nf * 16 + (l & 15);
                bf[nf] = *(const bf16x8*)((const char*)Bls + row * 128 + (kb ^ ((row & 7) << 4)));
            }
#pragma unroll
            for (int mf = 0; mf < 4; ++mf)
#pragma unroll
                for (int nf = 0; nf < 4; ++nf)
                    acc[mf][nf] = __builtin_amdgcn_mfma_f32_16x16x32_bf16(
                        af[mf], bf[nf], acc[mf][nf], 0, 0, 0);
        }
        __syncthreads();
        if (ks + 1 < NS3) STORE(ks + 1);
    }
#undef A_LOAD
#undef B_LOAD
#undef STORE

    int hl = l & 15, lq = l >> 4;
#pragma unroll
    for (int mf = 0; mf < 4; ++mf)
#pragma unroll
        for (int reg = 0; reg < 4; ++reg) {
            int tl = wm * 64 + mf * 16 + lq * 4 + reg;
            int tgt = tgt_s[tl];
            float s = 0.f;
#pragma unroll
            for (int nf = 0; nf < 4; ++nf) {
                int hloc = wn * 64 + nf * 16 + hl;
                int h = blkN * 256 + hloc;
                float val = fmaf(acc[mf][nf][reg], SCALE_,
                                 base_s[hloc] + node_bias[(size_t)tgt * H_ + h]);
                float o = gelu_exact(val);
                s = fmaf(o, o, s);
            }
            s += __shfl_xor(s, 1, 64);
            s += __shfl_xor(s, 2, 64);
            s += __shfl_xor(s, 4, 64);
            s += __shfl_xor(s, 8, 64);
            if (hl == 0) red_s[tl * 4 + wn] = s;
        }
    __syncthreads();
    if (t < 128) {
        float s = red_s[t * 4] + red_s[t * 4 + 1] + red_s[t * 4 + 2] + red_s[t * 4 + 3];
        epart[(size_t)(trip0 + t) * 2 + blkN] = s;
    }
}

// ---------------------------------------------------------------------------
// loss (with energy finalize folded in)
__global__ void loss_kernel(const float* __restrict__ epart, float* __restrict__ out) {
    __shared__ float red[8];
    int t = threadIdx.x;  // 512 pairs
    float en[NN_];
    float mx = -1e30f;
#pragma unroll
    for (int n = 0; n < NN_; ++n) {
        int trip = t * NN_ + n;
        en[n] = sqrtf(epart[(size_t)trip * 2] + epart[(size_t)trip * 2 + 1]);
        mx = fmaxf(mx, en[n]);
    }
    float s = 0.f;
#pragma unroll
    for (int n = 0; n < NN_; ++n) s += expf(en[n] - mx);
    float li = logf(s) + mx - en[0];
#pragma unroll
    for (int off = 32; off; off >>= 1) li += __shfl_down(li, off, 64);
    if ((t & 63) == 0) red[t >> 6] = li;
    __syncthreads();
    if (t == 0) {
        float tot = 0.f;
#pragma unroll
        for (int w = 0; w < 8; ++w) tot += red[w];
        out[0] = tot / 512.0f;
    }
}

// ---------------------------------------------------------------------------
extern "C" void kernel_launch(void* const* d_in, const int* in_sizes, int n_in,
                              void* d_out, int out_size, void* d_ws, size_t ws_size,
                              hipStream_t stream) {
    const int*   nid       = (const int*)d_in[0];
    const float* node_emb  = (const float*)d_in[1];
    const float* wl_w      = (const float*)d_in[2];
    const float* wl_b      = (const float*)d_in[3];
    const float* wr_w      = (const float*)d_in[4];
    const float* wr_b      = (const float*)d_in[5];
    const float* bias_base = (const float*)d_in[6];
    const float* node_bias = (const float*)d_in[7];
    const float* positions = (const float*)d_in[8];
    float* out = (float*)d_out;

    float* ws      = (float*)d_ws;
    float* pe      = ws;                        // 33280
    float* e_all   = pe + 65 * H_;              // 262144
    float* U0      = e_all + 512 * H_;          // 2097152
    float* V0      = U0 + 512 * 4096;           // 2097152
    float* A2      = V0 + 512 * 4096;           // 1048576
    float* proj    = A2 + 512 * 2048;           // 131072
    float* epart   = proj + NT_ * R_;           // 32768
    unsigned short* e_bf  = (unsigned short*)(epart + 2 * NT_);   // 262144 sh
    unsigned short* W3    = e_bf + 512 * H_;                      // 512*2112 sh
    unsigned short* Wl_bf = W3 + 512 * KT3;                       // 1048576 sh
    unsigned short* Wr_bf = Wl_bf + 4096 * EMB_;                  // 1048576 sh
    unsigned short* WlT   = Wr_bf + 4096 * EMB_;                  // 1048576 sh
    unsigned short* E0    = WlT + 2048 * H_;                      // 262144 sh
    unsigned short* Etgt  = E0 + 1024 * EMB_;                     // 4194304 sh
    int* tgt_ids = (int*)(Etgt + (size_t)NT_ * EMB_);             // 16384

    prep_all<<<4233, 256, 0, stream>>>(nid, node_emb, wl_w, wr_w, node_bias,
                                       pe, e_all, Wl_bf, Wr_bf, E0);
    gemm_nt<<<dim3(4, 32, 2), 256, 0, stream>>>(
        E0, Wl_bf, wl_b, U0,
        E0 + 512 * EMB_, Wr_bf, wr_b, V0, 256, 4096);
    seq_prep<<<8 + 512 + 256 + 512, 256, 0, stream>>>(
        nid, positions, U0, V0, bias_base, node_bias, pe, e_all, e_bf,
        wr_w, wr_b, W3, wl_w, WlT, node_emb, Etgt, tgt_ids);
    gemm_nt<<<dim3(4, 16, 1), 256, 0, stream>>>(
        e_bf, WlT, nullptr, A2, e_bf, WlT, nullptr, A2, 512, 2048);
    proj_kernel<<<512, 512, 0, stream>>>(nid, node_emb, A2, e_all, wl_b, proj);
    gemm_v3<<<dim3(128, 2), 512, 0, stream>>>(W3, Etgt, tgt_ids, proj,
                                              bias_base, pe, node_bias, epart);
    loss_kernel<<<1, 512, 0, stream>>>(epart, out);
}